// Round 1
// baseline (1969.134 us; speedup 1.0000x reference)
//
#include <hip/hip_runtime.h>
#include <math.h>

#define B_SZ 32
#define T_LEN 2048
#define I_DIM 128
#define H_DIM 256
#define ROWS 32   // rows per workgroup in the two GEMM kernels

// ---------------------------------------------------------------------------
// Phase 1: xB[r][j] = sum_k x[r][k] * Bm[k][j]   (r < 65536, k < 128, j < 256)
// One WG = 256 threads; thread j owns output column j for 32 rows.
// x tile staged in LDS (reads are same-address broadcasts); Bm streamed
// coalesced (128 KB, L2-resident).
// ---------------------------------------------------------------------------
__global__ __launch_bounds__(256) void xb_proj(const float* __restrict__ x,
                                               const float* __restrict__ Bm,
                                               float* __restrict__ xB) {
    __shared__ float4 xt[ROWS][I_DIM / 4 + 1];   // +1 float4 pad vs write conflicts
    const int tid = threadIdx.x;
    const int j = tid;
    const long r0 = (long)blockIdx.x * ROWS;

    const float4* xg = (const float4*)(x + r0 * I_DIM);
#pragma unroll
    for (int i = 0; i < 4; ++i) {
        int f = tid + i * 256;           // 0..1023 float4s
        int rr = f >> 5;
        int kg = f & 31;
        xt[rr][kg] = xg[rr * 32 + kg];
    }
    __syncthreads();

    float acc[ROWS];
#pragma unroll
    for (int r = 0; r < ROWS; ++r) acc[r] = 0.f;

    for (int k = 0; k < I_DIM; k += 4) {
        float w0 = Bm[(k + 0) * H_DIM + j];
        float w1 = Bm[(k + 1) * H_DIM + j];
        float w2 = Bm[(k + 2) * H_DIM + j];
        float w3 = Bm[(k + 3) * H_DIM + j];
#pragma unroll
        for (int r = 0; r < ROWS; ++r) {
            float4 hv = xt[r][k >> 2];
            acc[r] = fmaf(hv.x, w0, acc[r]);
            acc[r] = fmaf(hv.y, w1, acc[r]);
            acc[r] = fmaf(hv.z, w2, acc[r]);
            acc[r] = fmaf(hv.w, w3, acc[r]);
        }
    }
#pragma unroll
    for (int r = 0; r < ROWS; ++r)
        xB[(r0 + r) * H_DIM + j] = acc[r];
}

// ---------------------------------------------------------------------------
// Phase 2: per-batch-chain recurrence, one WG (8 waves, 512 thr) per chain.
// A held entirely in registers across the WG: thread (j, kh) holds
// A[kh*128 .. kh*128+127][j]  (128 VGPRs). h broadcast via LDS.
// Writes h_t rows to hs (= d_out).
// ---------------------------------------------------------------------------
__global__ __launch_bounds__(512, 2) void rnn_scan(const float* __restrict__ A,
                                                   const float* __restrict__ xB,
                                                   float* __restrict__ hs) {
    __shared__ __align__(16) float h[H_DIM];
    __shared__ float red[H_DIM];
    const int tid = threadIdx.x;
    const int j = tid & 255;
    const int kh = tid >> 8;             // 0 or 1 : which K-half this thread sums
    const int b = blockIdx.x;

    float Areg[128];
#pragma unroll
    for (int kk = 0; kk < 128; ++kk)
        Areg[kk] = A[(kh * 128 + kk) * H_DIM + j];

    if (tid < H_DIM) h[tid] = 0.f;

    const float* xbp = xB + (long)b * T_LEN * H_DIM + j;
    float* hp = hs + (long)b * T_LEN * H_DIM + j;
    float xb_next = xbp[0];

    __syncthreads();

    for (int t = 0; t < T_LEN; ++t) {
        float p0 = 0.f, p1 = 0.f, p2 = 0.f, p3 = 0.f;
        const float4* h4 = (const float4*)&h[kh * 128];
#pragma unroll
        for (int kk = 0; kk < 128; kk += 4) {
            float4 hv = h4[kk >> 2];     // same addr across all 64 lanes: broadcast
            p0 = fmaf(hv.x, Areg[kk + 0], p0);
            p1 = fmaf(hv.y, Areg[kk + 1], p1);
            p2 = fmaf(hv.z, Areg[kk + 2], p2);
            p3 = fmaf(hv.w, Areg[kk + 3], p3);
        }
        float partial = (p0 + p1) + (p2 + p3);
        if (kh == 0) red[j] = partial;
        __syncthreads();
        if (kh == 1) {
            float y = partial + red[j] + xb_next;
            float hn = tanhf(y);
            h[j] = hn;
            hp[(long)t * H_DIM] = hn;                       // coalesced 1KB store
            if (t + 1 < T_LEN) xb_next = xbp[(long)(t + 1) * H_DIM];  // prefetch
        }
        __syncthreads();
    }
}

// ---------------------------------------------------------------------------
// Phase 3: out[r][j] = sum_k hs[r][k] * C[k][j]  — in place on d_out.
// Each WG stages its own 32 hs rows into LDS first, so the overwrite is safe.
// ---------------------------------------------------------------------------
__global__ __launch_bounds__(256) void out_proj(float* __restrict__ hs_out,
                                                const float* __restrict__ C) {
    __shared__ float4 ht[ROWS][H_DIM / 4 + 1];
    const int tid = threadIdx.x;
    const int j = tid;
    const long r0 = (long)blockIdx.x * ROWS;

    const float4* hg = (const float4*)(hs_out + r0 * H_DIM);
#pragma unroll
    for (int i = 0; i < 8; ++i) {
        int f = tid + i * 256;           // 0..2047 float4s
        int rr = f >> 6;
        int kg = f & 63;
        ht[rr][kg] = hg[rr * 64 + kg];
    }
    __syncthreads();

    float acc[ROWS];
#pragma unroll
    for (int r = 0; r < ROWS; ++r) acc[r] = 0.f;

    for (int k = 0; k < H_DIM; k += 4) {
        float w0 = C[(k + 0) * H_DIM + j];
        float w1 = C[(k + 1) * H_DIM + j];
        float w2 = C[(k + 2) * H_DIM + j];
        float w3 = C[(k + 3) * H_DIM + j];
#pragma unroll
        for (int r = 0; r < ROWS; ++r) {
            float4 hv = ht[r][k >> 2];
            acc[r] = fmaf(hv.x, w0, acc[r]);
            acc[r] = fmaf(hv.y, w1, acc[r]);
            acc[r] = fmaf(hv.z, w2, acc[r]);
            acc[r] = fmaf(hv.w, w3, acc[r]);
        }
    }
#pragma unroll
    for (int r = 0; r < ROWS; ++r)
        hs_out[(r0 + r) * H_DIM + j] = acc[r];
}

// ---------------------------------------------------------------------------
extern "C" void kernel_launch(void* const* d_in, const int* in_sizes, int n_in,
                              void* d_out, int out_size, void* d_ws, size_t ws_size,
                              hipStream_t stream) {
    const float* x  = (const float*)d_in[0];
    const float* A  = (const float*)d_in[1];
    const float* Bm = (const float*)d_in[2];
    const float* C  = (const float*)d_in[3];
    float* out = (float*)d_out;
    float* xB  = (float*)d_ws;   // 65536 * 256 * 4B = 64 MB scratch

    const int R = B_SZ * T_LEN;  // 65536 rows

    xb_proj<<<R / ROWS, 256, 0, stream>>>(x, Bm, xB);
    rnn_scan<<<B_SZ, 512, 0, stream>>>(A, xB, out);
    out_proj<<<R / ROWS, 256, 0, stream>>>(out, C);
}

// Round 2
// 1857.463 us; speedup vs baseline: 1.0601x; 1.0601x over previous
//
#include <hip/hip_runtime.h>
#include <math.h>

#define B_SZ 32
#define T_LEN 2048
#define I_DIM 128
#define H_DIM 256
#define ROWS 32   // rows per workgroup in the two GEMM kernels

// ---------------------------------------------------------------------------
// Phase 1: xB[r][j] = sum_k x[r][k] * Bm[k][j]   (r < 65536, k < 128, j < 256)
// ---------------------------------------------------------------------------
__global__ __launch_bounds__(256) void xb_proj(const float* __restrict__ x,
                                               const float* __restrict__ Bm,
                                               float* __restrict__ xB) {
    __shared__ float4 xt[ROWS][I_DIM / 4 + 1];
    const int tid = threadIdx.x;
    const int j = tid;
    const long r0 = (long)blockIdx.x * ROWS;

    const float4* xg = (const float4*)(x + r0 * I_DIM);
#pragma unroll
    for (int i = 0; i < 4; ++i) {
        int f = tid + i * 256;
        int rr = f >> 5;
        int kg = f & 31;
        xt[rr][kg] = xg[rr * 32 + kg];
    }
    __syncthreads();

    float acc[ROWS];
#pragma unroll
    for (int r = 0; r < ROWS; ++r) acc[r] = 0.f;

    for (int k = 0; k < I_DIM; k += 4) {
        float w0 = Bm[(k + 0) * H_DIM + j];
        float w1 = Bm[(k + 1) * H_DIM + j];
        float w2 = Bm[(k + 2) * H_DIM + j];
        float w3 = Bm[(k + 3) * H_DIM + j];
#pragma unroll
        for (int r = 0; r < ROWS; ++r) {
            float4 hv = xt[r][k >> 2];
            acc[r] = fmaf(hv.x, w0, acc[r]);
            acc[r] = fmaf(hv.y, w1, acc[r]);
            acc[r] = fmaf(hv.z, w2, acc[r]);
            acc[r] = fmaf(hv.w, w3, acc[r]);
        }
    }
#pragma unroll
    for (int r = 0; r < ROWS; ++r)
        xB[(r0 + r) * H_DIM + j] = acc[r];
}

// ---------------------------------------------------------------------------
// Phase 2: per-chain recurrence. One WG = 1024 threads (16 waves) per chain.
// Thread (s = tid&7, p = tid>>3) owns output columns p and p+128 over
// k-slice [32s, 32s+32): a0[32], a1[32] in VGPRs (64 total -> no spill under
// the 128-VGPR cap that 16 resident waves force).
// K-reduction: __shfl_xor over lane bits 1,2,4 (the 8 k-slices are the low
// 3 lane bits). h double-buffered in LDS with a 4-float skew per slice
// (stride 36 floats) so the 8 distinct ds_read_b128 addresses per wave hit
// disjoint bank groups. ONE barrier per step.
// ---------------------------------------------------------------------------
#define HS_STRIDE 36   // 32 floats + 4 pad: slice s starts at bank (4*s)%32

__global__ __launch_bounds__(1024) void rnn_scan(const float* __restrict__ A,
                                                 const float* __restrict__ xB,
                                                 float* __restrict__ hs) {
    __shared__ __align__(16) float h[2][8 * HS_STRIDE];
    const int tid = threadIdx.x;
    const int s = tid & 7;        // k-slice
    const int p = tid >> 3;       // 0..127: columns p and p+128
    const int b = blockIdx.x;

    // A fragments: a0[kk] = A[32s+kk][p], a1[kk] = A[32s+kk][p+128]
    float a0[32], a1[32];
#pragma unroll
    for (int kk = 0; kk < 32; ++kk) {
        a0[kk] = A[(s * 32 + kk) * H_DIM + p];
        a1[kk] = A[(s * 32 + kk) * H_DIM + p + 128];
    }

    if (tid < 2 * 8 * HS_STRIDE) ((float*)h)[tid] = 0.f;   // zero both buffers' slots

    const long base = (long)b * T_LEN * H_DIM;
    const int jw = (s == 1) ? (p + 128) : p;   // column this lane writes (if s<2)
    const float* xbp = xB + base + jw;
    float* hp = hs + base + jw;
    float xbn = (s < 2) ? xbp[0] : 0.f;        // prefetched xB for step t

    __syncthreads();

    for (int t = 0; t < T_LEN; ++t) {
        const float4* h4 = (const float4*)(&h[t & 1][0] + s * HS_STRIDE);
        float y0a = 0.f, y0b = 0.f, y1a = 0.f, y1b = 0.f;
#pragma unroll
        for (int kk = 0; kk < 8; kk += 2) {
            float4 hva = h4[kk];
            float4 hvb = h4[kk + 1];
            y0a = fmaf(hva.x, a0[kk * 4 + 0], y0a);
            y0a = fmaf(hva.y, a0[kk * 4 + 1], y0a);
            y0a = fmaf(hva.z, a0[kk * 4 + 2], y0a);
            y0a = fmaf(hva.w, a0[kk * 4 + 3], y0a);
            y1a = fmaf(hva.x, a1[kk * 4 + 0], y1a);
            y1a = fmaf(hva.y, a1[kk * 4 + 1], y1a);
            y1a = fmaf(hva.z, a1[kk * 4 + 2], y1a);
            y1a = fmaf(hva.w, a1[kk * 4 + 3], y1a);
            y0b = fmaf(hvb.x, a0[kk * 4 + 4], y0b);
            y0b = fmaf(hvb.y, a0[kk * 4 + 5], y0b);
            y0b = fmaf(hvb.z, a0[kk * 4 + 6], y0b);
            y0b = fmaf(hvb.w, a0[kk * 4 + 7], y0b);
            y1b = fmaf(hvb.x, a1[kk * 4 + 4], y1b);
            y1b = fmaf(hvb.y, a1[kk * 4 + 5], y1b);
            y1b = fmaf(hvb.z, a1[kk * 4 + 6], y1b);
            y1b = fmaf(hvb.w, a1[kk * 4 + 7], y1b);
        }
        float y0 = y0a + y0b;
        float y1 = y1a + y1b;
        // reduce the 8 k-slices (lane bits 0..2)
        y0 += __shfl_xor(y0, 1); y1 += __shfl_xor(y1, 1);
        y0 += __shfl_xor(y0, 2); y1 += __shfl_xor(y1, 2);
        y0 += __shfl_xor(y0, 4); y1 += __shfl_xor(y1, 4);

        if (s < 2) {
            float y = ((s == 0) ? y0 : y1) + xbn;
            // fast tanh: 1 - 2/(e^{2y}+1); saturates correctly for |y| large
            float e = __expf(2.f * y);
            float hn = 1.f - 2.f / (e + 1.f);
            h[(t + 1) & 1][((jw >> 5) * HS_STRIDE) + (jw & 31)] = hn;
            hp[(long)t * H_DIM] = hn;
            if (t + 1 < T_LEN) xbn = xbp[(long)(t + 1) * H_DIM];
        }
        __syncthreads();
    }
}

// ---------------------------------------------------------------------------
// Phase 3: out[r][j] = sum_k hs[r][k] * C[k][j]  — in place on d_out.
// ---------------------------------------------------------------------------
__global__ __launch_bounds__(256) void out_proj(float* __restrict__ hs_out,
                                                const float* __restrict__ C) {
    __shared__ float4 ht[ROWS][H_DIM / 4 + 1];
    const int tid = threadIdx.x;
    const int j = tid;
    const long r0 = (long)blockIdx.x * ROWS;

    const float4* hg = (const float4*)(hs_out + r0 * H_DIM);
#pragma unroll
    for (int i = 0; i < 8; ++i) {
        int f = tid + i * 256;
        int rr = f >> 6;
        int kg = f & 63;
        ht[rr][kg] = hg[rr * 64 + kg];
    }
    __syncthreads();

    float acc[ROWS];
#pragma unroll
    for (int r = 0; r < ROWS; ++r) acc[r] = 0.f;

    for (int k = 0; k < H_DIM; k += 4) {
        float w0 = C[(k + 0) * H_DIM + j];
        float w1 = C[(k + 1) * H_DIM + j];
        float w2 = C[(k + 2) * H_DIM + j];
        float w3 = C[(k + 3) * H_DIM + j];
#pragma unroll
        for (int r = 0; r < ROWS; ++r) {
            float4 hv = ht[r][k >> 2];
            acc[r] = fmaf(hv.x, w0, acc[r]);
            acc[r] = fmaf(hv.y, w1, acc[r]);
            acc[r] = fmaf(hv.z, w2, acc[r]);
            acc[r] = fmaf(hv.w, w3, acc[r]);
        }
    }
#pragma unroll
    for (int r = 0; r < ROWS; ++r)
        hs_out[(r0 + r) * H_DIM + j] = acc[r];
}

// ---------------------------------------------------------------------------
extern "C" void kernel_launch(void* const* d_in, const int* in_sizes, int n_in,
                              void* d_out, int out_size, void* d_ws, size_t ws_size,
                              hipStream_t stream) {
    const float* x  = (const float*)d_in[0];
    const float* A  = (const float*)d_in[1];
    const float* Bm = (const float*)d_in[2];
    const float* C  = (const float*)d_in[3];
    float* out = (float*)d_out;
    float* xB  = (float*)d_ws;   // 64 MB scratch

    const int R = B_SZ * T_LEN;  // 65536 rows

    xb_proj<<<R / ROWS, 256, 0, stream>>>(x, Bm, xB);
    rnn_scan<<<B_SZ, 1024, 0, stream>>>(A, xB, out);
    out_proj<<<R / ROWS, 256, 0, stream>>>(out, C);
}